// Round 14
// baseline (3599.728 us; speedup 1.0000x reference)
//
#include <hip/hip_runtime.h>

// GRU scan, T=512 B=64 D=1024. Persistent cooperative kernel.
// R13 skeleton: 256 WGs = 4 mgrps x 64 col-WGs; 512 thr (8 waves, K 128/wave);
// weights persistent in registers; x pre-split to bf16 hi/lo planes in d_out;
// octet-split barrier + per-WG coalesced arrivals (LDS rendezvous, +4).
// R14 change (ONE structural variable): NO post-arrive tail. x(t+1) issued
// right after the poll (oldest in vm queue -> drains under the h-load waits);
// gi(t+1) MFMAs run right after gh (x drained by WAITN(0)); pgh+pgi published
// together before ONE mid-step sync; pgi double-buffered; loop-end sync
// protects pgi cross-iteration. Producer arrive-drain = WAITN(1) (out-store
// stays in flight; next poll's own vmcnt(0) drains it off the arrive path).

typedef __attribute__((ext_vector_type(8))) short short8;
typedef __attribute__((ext_vector_type(4))) float f32x4;
typedef __attribute__((ext_vector_type(4))) unsigned int u32x4;

#define DEV static __device__ __forceinline__

constexpr int TT = 512, BB = 64, DD = 1024, TD = 3072;

constexpr size_t WS_BAR = 256;                 // barrier area: 4 mgrps x 256 words
constexpr size_t WS_H = 8192;                  // h planes: hb0_hi, hb0_lo, hb1_hi, hb1_lo
constexpr size_t HPLANE = (size_t)BB * DD * 2; // 128 KB per plane
constexpr size_t WS_NEED = WS_H + 4 * HPLANE;

DEV unsigned short f2bf(float f) {   // RNE float->bf16
    unsigned u = __builtin_bit_cast(unsigned, f);
    u += 0x7FFFu + ((u >> 16) & 1u);
    return (unsigned short)(u >> 16);
}
DEV float bf2f(unsigned short s) { return __builtin_bit_cast(float, ((unsigned)s) << 16); }

DEV void ld16c(u32x4& r, const unsigned* p) {   // coherent 16B load (L1+L2 bypass)
    asm volatile("global_load_dwordx4 %0, %1, off sc0 sc1" : "=v"(r) : "v"(p));
}
DEV void ld16(u32x4& r, const unsigned* p) {    // plain cached 16B load
    asm volatile("global_load_dwordx4 %0, %1, off" : "=v"(r) : "v"(p));
}
DEV void ld8u(unsigned& r, const unsigned char* p) {
    asm volatile("global_load_ubyte %0, %1, off" : "=v"(r) : "v"(p));
}
DEV void vm0() {
    asm volatile("s_waitcnt vmcnt(0)" ::: "memory");
    __builtin_amdgcn_sched_barrier(0);   // rule #18
}
#define WAITN(n) do { asm volatile("s_waitcnt vmcnt(" #n ")" ::: "memory"); \
                      __builtin_amdgcn_sched_barrier(0); } while (0)

// ---------------- prepass A: split x into bf16 hi/lo planes, MGRP-LOCAL layout ----------------
// plane t (65536 words): mgrp m: words [m*16384, +8192) = x_hi rows m*16..+16,
//                        words [m*16384+8192, +8192) = x_lo same rows.
__global__ void pack_x_kernel(const float* __restrict__ x, unsigned* __restrict__ outw) {
    const size_t gid = (size_t)blockIdx.x * 256 + threadIdx.x;
    const size_t e0 = gid * 8;
    const unsigned t = (unsigned)(e0 >> 16);
    const unsigned p = (unsigned)(e0 & 65535u);
    const unsigned r = p >> 10, d = p & 1023u;
    const unsigned m = r >> 4, lr = r & 15u;
    f32x4 a = *(const f32x4*)(x + e0);
    f32x4 b = *(const f32x4*)(x + e0 + 4);
    u32x4 wh, wl;
#pragma unroll
    for (int j = 0; j < 2; ++j) {
        unsigned short h0 = f2bf(a[2 * j]), h1 = f2bf(a[2 * j + 1]);
        wh[j] = (unsigned)h0 | ((unsigned)h1 << 16);
        wl[j] = (unsigned)f2bf(a[2 * j] - bf2f(h0)) | ((unsigned)f2bf(a[2 * j + 1] - bf2f(h1)) << 16);
        unsigned short g0 = f2bf(b[2 * j]), g1 = f2bf(b[2 * j + 1]);
        wh[2 + j] = (unsigned)g0 | ((unsigned)g1 << 16);
        wl[2 + j] = (unsigned)f2bf(b[2 * j] - bf2f(g0)) | ((unsigned)f2bf(b[2 * j + 1] - bf2f(g1)) << 16);
    }
    unsigned* base = outw + (size_t)t * 65536u + m * 16384u + ((lr * 1024u + d) >> 1);
    *(u32x4*)base = wh;
    *(u32x4*)(base + 8192u) = wl;
}

// ---------------- prepass B: zero h-buf0 + barrier area, detect resets stride ----------------
__global__ void prep_kernel(const unsigned char* __restrict__ resets, unsigned char* __restrict__ ws) {
    const int bid = blockIdx.x, tid = threadIdx.x;
    if (bid < 256) {
        ((unsigned*)(ws + WS_H))[bid * 256 + tid] = 0u;   // zero hb0 hi+lo (256 KB)
    } else {
        unsigned* w32 = (unsigned*)ws;
        for (int i = tid; i < 2048; i += 256) w32[i] = 0u;
        __shared__ int ca, cb, cc;
        if (tid == 0) { ca = 0; cb = 0; cc = 0; }
        __syncthreads();
        int la = 0, lb = 0, lc = 0;
        for (int o = tid * 16; o < tid * 16 + 16; ++o) {
            unsigned char v = resets[o];
            if (v) {
                if ((o & 3) == 0) la = 1; else lb = 1;
                if ((o & 7) == 4) lc = 1;
            }
        }
        if (la) atomicOr(&ca, 1);
        if (lb) atomicOr(&cb, 1);
        if (lc) atomicOr(&cc, 1);
        __syncthreads();
        if (tid == 0) {
            unsigned stride, boff = 0;
            if (ca && cb)       { stride = 1; }
            else if (!ca && cb) { stride = 4; boff = 3; }
            else if (ca && cc)  { stride = 4; }
            else if (ca)        { stride = 8; }
            else                { stride = 4; }
            w32[0] = stride; w32[1] = boff;
        }
    }
}

// ---------------- main persistent kernel ----------------
__launch_bounds__(512, 1)
__global__ void gru_kernel(const float* __restrict__ Wi, const float* __restrict__ bi,
                           const float* __restrict__ Wh, const float* __restrict__ bhn,
                           const unsigned char* __restrict__ resets,
                           float* __restrict__ out, unsigned char* __restrict__ ws) {
    const int tid = threadIdx.x;
    const int wg = blockIdx.x;
    const int lane = tid & 63;
    const int kw = tid >> 6;
    const int mgrp = wg >> 6;
    const int cg = wg & 63;
    const int c0 = cg * 16;

    unsigned* bar = (unsigned*)(ws + WS_BAR) + mgrp * 256;   // 8 octet ctrs at o*32 words
    unsigned* myctr  = &bar[kw * 32];          // the counter THIS wave polls
    unsigned* arrctr = &bar[(cg >> 3) * 32];   // the counter this WG's producers bump
    const unsigned rstride = ((const unsigned*)ws)[0];
    const unsigned rboff   = ((const unsigned*)ws)[1];

    unsigned short* h_hi[2] = {(unsigned short*)(ws + WS_H),
                               (unsigned short*)(ws + WS_H + 2 * HPLANE)};
    unsigned short* h_lo[2] = {(unsigned short*)(ws + WS_H + HPLANE),
                               (unsigned short*)(ws + WS_H + 3 * HPLANE)};
    unsigned* outw = (unsigned*)out;

    const int lrow = lane & 15;
    const int lk = (lane >> 4) * 8;

    // ---- persistent B fragments (Wi_hi, Wh_hi, Wh_lo) ----
    short8 bih[3][4], bhh[3][4], bhl[3][4];
#pragma unroll
    for (int nt = 0; nt < 3; ++nt) {
        const int col = nt * DD + c0 + lrow;
#pragma unroll
        for (int kt = 0; kt < 4; ++kt) {
            const int kb = kw * 128 + kt * 32 + lk;
            short8 a, c, d;
#pragma unroll
            for (int j = 0; j < 8; ++j) {
                float wi = Wi[(size_t)(kb + j) * TD + col];
                a[j] = (short)f2bf(wi);
                float wh = Wh[(size_t)(kb + j) * TD + col];
                unsigned short h2 = f2bf(wh);
                c[j] = (short)h2;
                d[j] = (short)f2bf(wh - bf2f(h2));
            }
            bih[nt][kt] = a; bhh[nt][kt] = c; bhl[nt][kt] = d;
        }
    }

    // ---- epilogue constants ----
    const int eb = (tid & 255) >> 4, ej = tid & 15;
    const int brow = mgrp * 16 + eb;
    const int ce = c0 + ej;
    const float bi_r = bi[ce], bi_z = bi[DD + ce], bi_n = bi[2 * DD + ce];
    const float bh_n = bhn[ce];
    float h_local = 0.f;
    float ys_prev = 0.f;

    const unsigned xlidx = (unsigned)(lrow * 1024 + kw * 128 + lk);
    const unsigned xwbase = (unsigned)mgrp * 16384u + (xlidx >> 1);
    const unsigned hidx = (unsigned)((mgrp * 16 + lrow) * 1024 + kw * 128 + lk);
    const size_t r64 = (size_t)64 * rstride;
    const size_t roffb = (size_t)brow * rstride + rboff;

    __shared__ float pgi[2][8][3][16][18];   // double-buffered gi partials
    __shared__ float pgh[8][3][16][18];
    __shared__ int wgarr;                    // producer-wave rendezvous (monotonic)
    const int prow = (lane >> 4) * 4;

    // ================= prologue: gi(0) into pgi[0] =================
    {
        if (tid == 0) wgarr = 0;
        const unsigned* xpl = outw;   // plane 0
        u32x4 xf0[8];
#pragma unroll
        for (int kt = 0; kt < 4; ++kt) {
            ld16(xf0[2 * kt],     xpl + xwbase + kt * 16);
            ld16(xf0[2 * kt + 1], xpl + xwbase + 8192u + kt * 16);
        }
        vm0();
        f32x4 ai[3] = {f32x4{0}, f32x4{0}, f32x4{0}};
#pragma unroll
        for (int kt = 0; kt < 4; ++kt) {
            short8 xh = __builtin_bit_cast(short8, xf0[2 * kt]);
            short8 xl = __builtin_bit_cast(short8, xf0[2 * kt + 1]);
#pragma unroll
            for (int nt = 0; nt < 3; ++nt)
                ai[nt] = __builtin_amdgcn_mfma_f32_16x16x32_bf16(xh, bih[nt][kt], ai[nt], 0, 0, 0);
#pragma unroll
            for (int nt = 0; nt < 3; ++nt)
                ai[nt] = __builtin_amdgcn_mfma_f32_16x16x32_bf16(xl, bih[nt][kt], ai[nt], 0, 0, 0);
        }
#pragma unroll
        for (int s = 0; s < 3; ++s)
#pragma unroll
            for (int i = 0; i < 4; ++i)
                pgi[0][kw][s][prow + i][lrow] = ai[s][i];
        __syncthreads();
    }

    // ================= main loop =================
    for (int t = 0; t < TT; ++t) {
        // (a) per-wave OCTET poll: counter[kw] >= 32*t. The poll's own vmcnt(0)
        //     also drains the previous iteration's leftover out-store.
        if (t) {
            const unsigned target = 32u * (unsigned)t;
            int guard = 1 << 20;       // bounded spin: fail loud, never hang
            unsigned s;
            do {
                s = __hip_atomic_load(myctr, __ATOMIC_RELAXED, __HIP_MEMORY_SCOPE_AGENT);
            } while (s < target && --guard);
        }
        __builtin_amdgcn_sched_barrier(0);

        const int tn = (t + 1 < TT) ? (t + 1) : (TT - 1);

        // (a2) issue x(t+1) FIRST (oldest in queue -> drains under the h waits)
        u32x4 xf[8];
        {
            const unsigned* xpl = outw + (size_t)tn * 65536u;
#pragma unroll
            for (int kt = 0; kt < 4; ++kt) {
                ld16(xf[2 * kt],     xpl + xwbase + kt * 16);
                ld16(xf[2 * kt + 1], xpl + xwbase + 8192u + kt * 16);
            }
        }

        // (b) issue: rsv byte + coherent h(t) loads  (queue: [x8][rsv][h8] = 17)
        unsigned rsv;
        ld8u(rsv, resets + roffb + (size_t)tn * r64);
        const int cur = t & 1;
        const unsigned* hhp = (const unsigned*)h_hi[cur];
        const unsigned* hlp = (const unsigned*)h_lo[cur];
        u32x4 hf[8];
#pragma unroll
        for (int kt = 0; kt < 4; ++kt) {
            ld16c(hf[2 * kt],     hhp + ((hidx + kt * 32) >> 1));
            ld16c(hf[2 * kt + 1], hlp + ((hidx + kt * 32) >> 1));
        }

        // (c) gi reduce from pgi[t&1] (LDS only, hides load latency)
        float g0 = 0.f, g1 = 0.f, g2 = 0.f;
        if (tid < 256) {
#pragma unroll
            for (int k = 0; k < 8; ++k) {
                g0 += pgi[cur][k][0][eb][ej];
                g1 += pgi[cur][k][1][eb][ej];
                g2 += pgi[cur][k][2][eb][ej];
            }
        }

        // (d) gh MFMAs, counted waits; WAITN(6) also drains x8+rsv
        f32x4 ag[3] = {f32x4{0}, f32x4{0}, f32x4{0}};
        __builtin_amdgcn_s_setprio(1);
        {
            WAITN(6);
            short8 hh = __builtin_bit_cast(short8, hf[0]);
            short8 hl = __builtin_bit_cast(short8, hf[1]);
#pragma unroll
            for (int nt = 0; nt < 3; ++nt) {
                ag[nt] = __builtin_amdgcn_mfma_f32_16x16x32_bf16(hh, bhh[nt][0], ag[nt], 0, 0, 0);
                ag[nt] = __builtin_amdgcn_mfma_f32_16x16x32_bf16(hl, bhh[nt][0], ag[nt], 0, 0, 0);
                ag[nt] = __builtin_amdgcn_mfma_f32_16x16x32_bf16(hh, bhl[nt][0], ag[nt], 0, 0, 0);
            }
        }
        {
            WAITN(4);
            short8 hh = __builtin_bit_cast(short8, hf[2]);
            short8 hl = __builtin_bit_cast(short8, hf[3]);
#pragma unroll
            for (int nt = 0; nt < 3; ++nt) {
                ag[nt] = __builtin_amdgcn_mfma_f32_16x16x32_bf16(hh, bhh[nt][1], ag[nt], 0, 0, 0);
                ag[nt] = __builtin_amdgcn_mfma_f32_16x16x32_bf16(hl, bhh[nt][1], ag[nt], 0, 0, 0);
                ag[nt] = __builtin_amdgcn_mfma_f32_16x16x32_bf16(hh, bhl[nt][1], ag[nt], 0, 0, 0);
            }
        }
        {
            WAITN(2);
            short8 hh = __builtin_bit_cast(short8, hf[4]);
            short8 hl = __builtin_bit_cast(short8, hf[5]);
#pragma unroll
            for (int nt = 0; nt < 3; ++nt) {
                ag[nt] = __builtin_amdgcn_mfma_f32_16x16x32_bf16(hh, bhh[nt][2], ag[nt], 0, 0, 0);
                ag[nt] = __builtin_amdgcn_mfma_f32_16x16x32_bf16(hl, bhh[nt][2], ag[nt], 0, 0, 0);
                ag[nt] = __builtin_amdgcn_mfma_f32_16x16x32_bf16(hh, bhl[nt][2], ag[nt], 0, 0, 0);
            }
        }
        {
            WAITN(0);   // h done AND x done
            short8 hh = __builtin_bit_cast(short8, hf[6]);
            short8 hl = __builtin_bit_cast(short8, hf[7]);
#pragma unroll
            for (int nt = 0; nt < 3; ++nt) {
                ag[nt] = __builtin_amdgcn_mfma_f32_16x16x32_bf16(hh, bhh[nt][3], ag[nt], 0, 0, 0);
                ag[nt] = __builtin_amdgcn_mfma_f32_16x16x32_bf16(hl, bhh[nt][3], ag[nt], 0, 0, 0);
                ag[nt] = __builtin_amdgcn_mfma_f32_16x16x32_bf16(hh, bhl[nt][3], ag[nt], 0, 0, 0);
            }
        }

        // (d2) gi(t+1) MFMAs from xf (registers; drained above), no tail later
        f32x4 ai[3] = {f32x4{0}, f32x4{0}, f32x4{0}};
#pragma unroll
        for (int kt = 0; kt < 4; ++kt) {
            short8 xh = __builtin_bit_cast(short8, xf[2 * kt]);
            short8 xl = __builtin_bit_cast(short8, xf[2 * kt + 1]);
#pragma unroll
            for (int nt = 0; nt < 3; ++nt)
                ai[nt] = __builtin_amdgcn_mfma_f32_16x16x32_bf16(xh, bih[nt][kt], ai[nt], 0, 0, 0);
#pragma unroll
            for (int nt = 0; nt < 3; ++nt)
                ai[nt] = __builtin_amdgcn_mfma_f32_16x16x32_bf16(xl, bih[nt][kt], ai[nt], 0, 0, 0);
        }
        __builtin_amdgcn_s_setprio(0);

        // (e) publish gh(t) + gi(t+1), one sync
#pragma unroll
        for (int s = 0; s < 3; ++s)
#pragma unroll
            for (int i = 0; i < 4; ++i) {
                pgh[kw][s][prow + i][lrow] = ag[s][i];
                pgi[cur ^ 1][kw][s][prow + i][lrow] = ai[s][i];
            }
        __syncthreads();

        // (f) epilogue (waves 0-3): gates, h(t+1) stores FIRST, then out(t-1)
        if (tid < 256) {
            float h0 = 0.f, h1 = 0.f, h2 = 0.f;
#pragma unroll
            for (int k = 0; k < 8; ++k) {
                h0 += pgh[k][0][eb][ej];
                h1 += pgh[k][1][eb][ej];
                h2 += pgh[k][2][eb][ej];
            }
            float r = 1.f / (1.f + __expf(-(g0 + bi_r + h0)));
            float z = 1.f / (1.f + __expf(-(g1 + bi_z + h1)));
            float pre = g2 + bi_n + r * (h2 + bh_n);
            float e2 = __expf(2.f * pre);
            float n = 1.f - 2.f / (e2 + 1.f);
            float hnew = (1.f - z) * n + z * h_local;

            if (t < TT - 1) {
                float heff = (rsv != 0u) ? 0.f : hnew;   // rsv drained by WAITN(6)
                h_local = heff;
                unsigned short ph = f2bf(heff);
                unsigned short pl = f2bf(heff - bf2f(ph));
                __hip_atomic_store(h_hi[cur ^ 1] + brow * DD + ce, ph,
                                   __ATOMIC_RELAXED, __HIP_MEMORY_SCOPE_AGENT);
                __hip_atomic_store(h_lo[cur ^ 1] + brow * DD + ce, pl,
                                   __ATOMIC_RELAXED, __HIP_MEMORY_SCOPE_AGENT);
            }
            if (t) out[(size_t)(t - 1) * 65536u + brow * DD + ce] = ys_prev;
            ys_prev = hnew;
        }

        // (h) producers: drain h stores only (out stays in flight), rendezvous,
        //     4th wave publishes ONE +4 arrival.
        if (kw < 4 && t < TT - 1) {
            if (t == 0) { WAITN(0); } else { WAITN(1); }   // t==0: no out store in queue
            if (lane == 0) {
                int old = atomicAdd(&wgarr, 1);
                if ((old & 3) == 3)
                    __hip_atomic_fetch_add(arrctr, 4u, __ATOMIC_RELAXED, __HIP_MEMORY_SCOPE_AGENT);
            }
        }

        // (j) loop-end sync: protects pgi[t&1] reads (f) vs next iter's (e) writes
        __syncthreads();
    }

    if (tid < 256)
        out[(size_t)(TT - 1) * 65536u + brow * DD + ce] = ys_prev;
}

extern "C" void kernel_launch(void* const* d_in, const int* in_sizes, int n_in,
                              void* d_out, int out_size, void* d_ws, size_t ws_size,
                              hipStream_t stream) {
    const float* x = (const float*)d_in[0];
    const float* Wi = (const float*)d_in[1];
    const float* bi = (const float*)d_in[2];
    const float* Wh = (const float*)d_in[3];
    const float* bhn = (const float*)d_in[4];
    const unsigned char* resets = (const unsigned char*)d_in[5];
    float* out = (float*)d_out;
    unsigned char* ws = (unsigned char*)d_ws;

    if (ws_size < WS_NEED) return;

    hipLaunchKernelGGL(pack_x_kernel, dim3(16384), dim3(256), 0, stream, x, (unsigned*)out);
    hipLaunchKernelGGL(prep_kernel, dim3(257), dim3(256), 0, stream, resets, ws);

    void* args[] = {(void*)&Wi, (void*)&bi, (void*)&Wh, (void*)&bhn,
                    (void*)&resets, (void*)&out, (void*)&ws};
    hipError_t err = hipLaunchCooperativeKernel((const void*)gru_kernel, dim3(256), dim3(512),
                                                args, 0, stream);
    if (err != hipSuccess) {
        hipLaunchKernelGGL(gru_kernel, dim3(256), dim3(512), 0, stream,
                           Wi, bi, Wh, bhn, resets, out, ws);
    }
}

// Round 15
// 2629.548 us; speedup vs baseline: 1.3690x; 1.3690x over previous
//
#include <hip/hip_runtime.h>

// GRU scan, T=512 B=64 D=1024. Persistent cooperative kernel.
// BEST CONFIGURATION (R13, 2621 us): 256 WGs = 4 mgrps x 64 col-WGs; 512 thr
// (8 waves, K 128/wave); weights persistent in registers; x pre-split to bf16
// hi/lo planes in d_out; octet-split barrier (wave kw polls counter[kw]>=32t);
// per-WG coalesced arrivals (LDS rendezvous, one +4 RMW); out(t-1) deferred;
// x(t+1) issued AFTER stores (keeps x latency off the h critical path — the
// R14 lesson: in-order vmcnt puts anything issued before h onto h's path).
// Structural floor: per-step serial chain = poll-detect (~1.5 LLC RT) +
// h-load RT + store-drain RT + ~1.3us compute ≈ 5.1us/step at ~0.9us/RT.

typedef __attribute__((ext_vector_type(8))) short short8;
typedef __attribute__((ext_vector_type(4))) float f32x4;
typedef __attribute__((ext_vector_type(4))) unsigned int u32x4;

#define DEV static __device__ __forceinline__

constexpr int TT = 512, BB = 64, DD = 1024, TD = 3072;

constexpr size_t WS_BAR = 256;                 // barrier area: 4 mgrps x 256 words
constexpr size_t WS_H = 8192;                  // h planes: hb0_hi, hb0_lo, hb1_hi, hb1_lo
constexpr size_t HPLANE = (size_t)BB * DD * 2; // 128 KB per plane
constexpr size_t WS_NEED = WS_H + 4 * HPLANE;

DEV unsigned short f2bf(float f) {   // RNE float->bf16
    unsigned u = __builtin_bit_cast(unsigned, f);
    u += 0x7FFFu + ((u >> 16) & 1u);
    return (unsigned short)(u >> 16);
}
DEV float bf2f(unsigned short s) { return __builtin_bit_cast(float, ((unsigned)s) << 16); }

DEV void ld16c(u32x4& r, const unsigned* p) {   // coherent 16B load (L1+L2 bypass)
    asm volatile("global_load_dwordx4 %0, %1, off sc0 sc1" : "=v"(r) : "v"(p));
}
DEV void ld16(u32x4& r, const unsigned* p) {    // plain cached 16B load
    asm volatile("global_load_dwordx4 %0, %1, off" : "=v"(r) : "v"(p));
}
DEV void ld8u(unsigned& r, const unsigned char* p) {
    asm volatile("global_load_ubyte %0, %1, off" : "=v"(r) : "v"(p));
}
DEV void vm0() {
    asm volatile("s_waitcnt vmcnt(0)" ::: "memory");
    __builtin_amdgcn_sched_barrier(0);   // rule #18
}
#define WAITN(n) do { asm volatile("s_waitcnt vmcnt(" #n ")" ::: "memory"); \
                      __builtin_amdgcn_sched_barrier(0); } while (0)

// ---------------- prepass A: split x into bf16 hi/lo planes, MGRP-LOCAL layout ----------------
// plane t (65536 words): mgrp m: words [m*16384, +8192) = x_hi rows m*16..+16,
//                        words [m*16384+8192, +8192) = x_lo same rows.
__global__ void pack_x_kernel(const float* __restrict__ x, unsigned* __restrict__ outw) {
    const size_t gid = (size_t)blockIdx.x * 256 + threadIdx.x;
    const size_t e0 = gid * 8;
    const unsigned t = (unsigned)(e0 >> 16);
    const unsigned p = (unsigned)(e0 & 65535u);
    const unsigned r = p >> 10, d = p & 1023u;
    const unsigned m = r >> 4, lr = r & 15u;
    f32x4 a = *(const f32x4*)(x + e0);
    f32x4 b = *(const f32x4*)(x + e0 + 4);
    u32x4 wh, wl;
#pragma unroll
    for (int j = 0; j < 2; ++j) {
        unsigned short h0 = f2bf(a[2 * j]), h1 = f2bf(a[2 * j + 1]);
        wh[j] = (unsigned)h0 | ((unsigned)h1 << 16);
        wl[j] = (unsigned)f2bf(a[2 * j] - bf2f(h0)) | ((unsigned)f2bf(a[2 * j + 1] - bf2f(h1)) << 16);
        unsigned short g0 = f2bf(b[2 * j]), g1 = f2bf(b[2 * j + 1]);
        wh[2 + j] = (unsigned)g0 | ((unsigned)g1 << 16);
        wl[2 + j] = (unsigned)f2bf(b[2 * j] - bf2f(g0)) | ((unsigned)f2bf(b[2 * j + 1] - bf2f(g1)) << 16);
    }
    unsigned* base = outw + (size_t)t * 65536u + m * 16384u + ((lr * 1024u + d) >> 1);
    *(u32x4*)base = wh;
    *(u32x4*)(base + 8192u) = wl;
}

// ---------------- prepass B: zero h-buf0 + barrier area, detect resets stride ----------------
__global__ void prep_kernel(const unsigned char* __restrict__ resets, unsigned char* __restrict__ ws) {
    const int bid = blockIdx.x, tid = threadIdx.x;
    if (bid < 256) {
        ((unsigned*)(ws + WS_H))[bid * 256 + tid] = 0u;   // zero hb0 hi+lo (256 KB)
    } else {
        unsigned* w32 = (unsigned*)ws;
        for (int i = tid; i < 2048; i += 256) w32[i] = 0u;
        __shared__ int ca, cb, cc;
        if (tid == 0) { ca = 0; cb = 0; cc = 0; }
        __syncthreads();
        int la = 0, lb = 0, lc = 0;
        for (int o = tid * 16; o < tid * 16 + 16; ++o) {
            unsigned char v = resets[o];
            if (v) {
                if ((o & 3) == 0) la = 1; else lb = 1;
                if ((o & 7) == 4) lc = 1;
            }
        }
        if (la) atomicOr(&ca, 1);
        if (lb) atomicOr(&cb, 1);
        if (lc) atomicOr(&cc, 1);
        __syncthreads();
        if (tid == 0) {
            unsigned stride, boff = 0;
            if (ca && cb)       { stride = 1; }
            else if (!ca && cb) { stride = 4; boff = 3; }
            else if (ca && cc)  { stride = 4; }
            else if (ca)        { stride = 8; }
            else                { stride = 4; }
            w32[0] = stride; w32[1] = boff;
        }
    }
}

// ---------------- main persistent kernel ----------------
__launch_bounds__(512, 1)
__global__ void gru_kernel(const float* __restrict__ Wi, const float* __restrict__ bi,
                           const float* __restrict__ Wh, const float* __restrict__ bhn,
                           const unsigned char* __restrict__ resets,
                           float* __restrict__ out, unsigned char* __restrict__ ws) {
    const int tid = threadIdx.x;
    const int wg = blockIdx.x;
    const int lane = tid & 63;
    const int kw = tid >> 6;
    const int mgrp = wg >> 6;
    const int cg = wg & 63;
    const int c0 = cg * 16;

    unsigned* bar = (unsigned*)(ws + WS_BAR) + mgrp * 256;   // 8 octet ctrs at o*32 words
    unsigned* myctr  = &bar[kw * 32];          // the counter THIS wave polls
    unsigned* arrctr = &bar[(cg >> 3) * 32];   // the counter this WG's producers bump
    const unsigned rstride = ((const unsigned*)ws)[0];
    const unsigned rboff   = ((const unsigned*)ws)[1];

    unsigned short* h_hi[2] = {(unsigned short*)(ws + WS_H),
                               (unsigned short*)(ws + WS_H + 2 * HPLANE)};
    unsigned short* h_lo[2] = {(unsigned short*)(ws + WS_H + HPLANE),
                               (unsigned short*)(ws + WS_H + 3 * HPLANE)};
    unsigned* outw = (unsigned*)out;

    const int lrow = lane & 15;
    const int lk = (lane >> 4) * 8;

    // ---- persistent B fragments (Wi_hi, Wh_hi, Wh_lo) ----
    short8 bih[3][4], bhh[3][4], bhl[3][4];
#pragma unroll
    for (int nt = 0; nt < 3; ++nt) {
        const int col = nt * DD + c0 + lrow;
#pragma unroll
        for (int kt = 0; kt < 4; ++kt) {
            const int kb = kw * 128 + kt * 32 + lk;
            short8 a, c, d;
#pragma unroll
            for (int j = 0; j < 8; ++j) {
                float wi = Wi[(size_t)(kb + j) * TD + col];
                a[j] = (short)f2bf(wi);
                float wh = Wh[(size_t)(kb + j) * TD + col];
                unsigned short h2 = f2bf(wh);
                c[j] = (short)h2;
                d[j] = (short)f2bf(wh - bf2f(h2));
            }
            bih[nt][kt] = a; bhh[nt][kt] = c; bhl[nt][kt] = d;
        }
    }

    // ---- epilogue constants ----
    const int eb = (tid & 255) >> 4, ej = tid & 15;
    const int brow = mgrp * 16 + eb;
    const int ce = c0 + ej;
    const float bi_r = bi[ce], bi_z = bi[DD + ce], bi_n = bi[2 * DD + ce];
    const float bh_n = bhn[ce];
    float h_local = 0.f;
    float ys_prev = 0.f;

    const unsigned xlidx = (unsigned)(lrow * 1024 + kw * 128 + lk);
    const unsigned xwbase = (unsigned)mgrp * 16384u + (xlidx >> 1);
    const unsigned hidx = (unsigned)((mgrp * 16 + lrow) * 1024 + kw * 128 + lk);
    const size_t r64 = (size_t)64 * rstride;
    const size_t roffb = (size_t)brow * rstride + rboff;

    __shared__ float pgi[8][3][16][18];
    __shared__ float pgh[8][3][16][18];
    __shared__ int wgarr;               // producer-wave rendezvous (monotonic)
    const int prow = (lane >> 4) * 4;

    // ================= prologue: gi(0) =================
    {
        if (tid == 0) wgarr = 0;
        const unsigned* xpl = outw;   // plane 0
        u32x4 xf0[8];
#pragma unroll
        for (int kt = 0; kt < 4; ++kt) {
            ld16(xf0[2 * kt],     xpl + xwbase + kt * 16);
            ld16(xf0[2 * kt + 1], xpl + xwbase + 8192u + kt * 16);
        }
        vm0();
        f32x4 ai[3] = {f32x4{0}, f32x4{0}, f32x4{0}};
#pragma unroll
        for (int kt = 0; kt < 4; ++kt) {
            short8 xh = __builtin_bit_cast(short8, xf0[2 * kt]);
            short8 xl = __builtin_bit_cast(short8, xf0[2 * kt + 1]);
#pragma unroll
            for (int nt = 0; nt < 3; ++nt)
                ai[nt] = __builtin_amdgcn_mfma_f32_16x16x32_bf16(xh, bih[nt][kt], ai[nt], 0, 0, 0);
#pragma unroll
            for (int nt = 0; nt < 3; ++nt)
                ai[nt] = __builtin_amdgcn_mfma_f32_16x16x32_bf16(xl, bih[nt][kt], ai[nt], 0, 0, 0);
        }
#pragma unroll
        for (int s = 0; s < 3; ++s)
#pragma unroll
            for (int i = 0; i < 4; ++i)
                pgi[kw][s][prow + i][lrow] = ai[s][i];
        __syncthreads();
    }

    // ================= main loop =================
    for (int t = 0; t < TT; ++t) {
        // (a) per-wave OCTET poll: counter[kw] >= 32*t (one wave-uniform load)
        if (t) {
            const unsigned target = 32u * (unsigned)t;
            int guard = 1 << 20;       // bounded spin: fail loud, never hang
            unsigned s;
            do {
                s = __hip_atomic_load(myctr, __ATOMIC_RELAXED, __HIP_MEMORY_SCOPE_AGENT);
            } while (s < target && --guard);
        }
        __builtin_amdgcn_sched_barrier(0);

        const int tn = (t + 1 < TT) ? (t + 1) : (TT - 1);

        // (b) issue: rsv byte + coherent h(t) loads  (queue: [rsv][h8] = 9)
        unsigned rsv;
        ld8u(rsv, resets + roffb + (size_t)tn * r64);
        const int cur = t & 1;
        const unsigned* hhp = (const unsigned*)h_hi[cur];
        const unsigned* hlp = (const unsigned*)h_lo[cur];
        u32x4 hf[8];
#pragma unroll
        for (int kt = 0; kt < 4; ++kt) {
            ld16c(hf[2 * kt],     hhp + ((hidx + kt * 32) >> 1));
            ld16c(hf[2 * kt + 1], hlp + ((hidx + kt * 32) >> 1));
        }

        // (c) gi reduce (LDS only, hides h latency)
        float g0 = 0.f, g1 = 0.f, g2 = 0.f;
        if (tid < 256) {
#pragma unroll
            for (int k = 0; k < 8; ++k) {
                g0 += pgi[k][0][eb][ej];
                g1 += pgi[k][1][eb][ej];
                g2 += pgi[k][2][eb][ej];
            }
        }

        // (d) gh MFMAs, counted waits per k-tile
        f32x4 ag[3] = {f32x4{0}, f32x4{0}, f32x4{0}};
        __builtin_amdgcn_s_setprio(1);
        {
            WAITN(6);
            short8 hh = __builtin_bit_cast(short8, hf[0]);
            short8 hl = __builtin_bit_cast(short8, hf[1]);
#pragma unroll
            for (int nt = 0; nt < 3; ++nt) {
                ag[nt] = __builtin_amdgcn_mfma_f32_16x16x32_bf16(hh, bhh[nt][0], ag[nt], 0, 0, 0);
                ag[nt] = __builtin_amdgcn_mfma_f32_16x16x32_bf16(hl, bhh[nt][0], ag[nt], 0, 0, 0);
                ag[nt] = __builtin_amdgcn_mfma_f32_16x16x32_bf16(hh, bhl[nt][0], ag[nt], 0, 0, 0);
            }
        }
        {
            WAITN(4);
            short8 hh = __builtin_bit_cast(short8, hf[2]);
            short8 hl = __builtin_bit_cast(short8, hf[3]);
#pragma unroll
            for (int nt = 0; nt < 3; ++nt) {
                ag[nt] = __builtin_amdgcn_mfma_f32_16x16x32_bf16(hh, bhh[nt][1], ag[nt], 0, 0, 0);
                ag[nt] = __builtin_amdgcn_mfma_f32_16x16x32_bf16(hl, bhh[nt][1], ag[nt], 0, 0, 0);
                ag[nt] = __builtin_amdgcn_mfma_f32_16x16x32_bf16(hh, bhl[nt][1], ag[nt], 0, 0, 0);
            }
        }
        {
            WAITN(2);
            short8 hh = __builtin_bit_cast(short8, hf[4]);
            short8 hl = __builtin_bit_cast(short8, hf[5]);
#pragma unroll
            for (int nt = 0; nt < 3; ++nt) {
                ag[nt] = __builtin_amdgcn_mfma_f32_16x16x32_bf16(hh, bhh[nt][2], ag[nt], 0, 0, 0);
                ag[nt] = __builtin_amdgcn_mfma_f32_16x16x32_bf16(hl, bhh[nt][2], ag[nt], 0, 0, 0);
                ag[nt] = __builtin_amdgcn_mfma_f32_16x16x32_bf16(hh, bhl[nt][2], ag[nt], 0, 0, 0);
            }
        }
        {
            WAITN(0);
            short8 hh = __builtin_bit_cast(short8, hf[6]);
            short8 hl = __builtin_bit_cast(short8, hf[7]);
#pragma unroll
            for (int nt = 0; nt < 3; ++nt) {
                ag[nt] = __builtin_amdgcn_mfma_f32_16x16x32_bf16(hh, bhh[nt][3], ag[nt], 0, 0, 0);
                ag[nt] = __builtin_amdgcn_mfma_f32_16x16x32_bf16(hl, bhh[nt][3], ag[nt], 0, 0, 0);
                ag[nt] = __builtin_amdgcn_mfma_f32_16x16x32_bf16(hh, bhl[nt][3], ag[nt], 0, 0, 0);
            }
        }
        __builtin_amdgcn_s_setprio(0);

        // (e) publish gh partials
#pragma unroll
        for (int s = 0; s < 3; ++s)
#pragma unroll
            for (int i = 0; i < 4; ++i)
                pgh[kw][s][prow + i][lrow] = ag[s][i];
        __syncthreads();

        // (f) epilogue (waves 0-3): gates, deferred out(t-1), premasked h(t+1)
        if (tid < 256) {
            float h0 = 0.f, h1 = 0.f, h2 = 0.f;
#pragma unroll
            for (int k = 0; k < 8; ++k) {
                h0 += pgh[k][0][eb][ej];
                h1 += pgh[k][1][eb][ej];
                h2 += pgh[k][2][eb][ej];
            }
            float r = 1.f / (1.f + __expf(-(g0 + bi_r + h0)));
            float z = 1.f / (1.f + __expf(-(g1 + bi_z + h1)));
            float pre = g2 + bi_n + r * (h2 + bh_n);
            float e2 = __expf(2.f * pre);
            float n = 1.f - 2.f / (e2 + 1.f);
            float hnew = (1.f - z) * n + z * h_local;

            if (t) out[(size_t)(t - 1) * 65536u + brow * DD + ce] = ys_prev;
            ys_prev = hnew;

            if (t < TT - 1) {
                float heff = (rsv != 0u) ? 0.f : hnew;   // rsv drained by WAITN(6)
                h_local = heff;
                unsigned short ph = f2bf(heff);
                unsigned short pl = f2bf(heff - bf2f(ph));
                __hip_atomic_store(h_hi[cur ^ 1] + brow * DD + ce, ph,
                                   __ATOMIC_RELAXED, __HIP_MEMORY_SCOPE_AGENT);
                __hip_atomic_store(h_lo[cur ^ 1] + brow * DD + ce, pl,
                                   __ATOMIC_RELAXED, __HIP_MEMORY_SCOPE_AGENT);
            }
        }
        asm volatile("" ::: "memory");   // pin store -> x-issue program order

        // (g) issue x(t+1) AFTER stores (drains under next poll, off arrive path)
        u32x4 xf[8];
        if (t < TT - 1) {
            const unsigned* xpl = outw + (size_t)(t + 1) * 65536u;
#pragma unroll
            for (int kt = 0; kt < 4; ++kt) {
                ld16(xf[2 * kt],     xpl + xwbase + kt * 16);
                ld16(xf[2 * kt + 1], xpl + xwbase + 8192u + kt * 16);
            }
        }

        // (h) producer waves: drain own stores, rendezvous in LDS; the 4th wave
        //     publishes ONE +4 arrival for the whole WG (8 RMWs/line/step).
        if (kw < 4 && t < TT - 1) {
            WAITN(8);
            if (lane == 0) {
                int old = atomicAdd(&wgarr, 1);
                if ((old & 3) == 3)
                    __hip_atomic_fetch_add(arrctr, 4u, __ATOMIC_RELAXED, __HIP_MEMORY_SCOPE_AGENT);
            }
        }

        // (i) tail: drain x, gi(t+1) MFMAs, publish, sync
        if (t < TT - 1) {
            WAITN(0);
            f32x4 ai[3] = {f32x4{0}, f32x4{0}, f32x4{0}};
#pragma unroll
            for (int kt = 0; kt < 4; ++kt) {
                short8 xh = __builtin_bit_cast(short8, xf[2 * kt]);
                short8 xl = __builtin_bit_cast(short8, xf[2 * kt + 1]);
#pragma unroll
                for (int nt = 0; nt < 3; ++nt)
                    ai[nt] = __builtin_amdgcn_mfma_f32_16x16x32_bf16(xh, bih[nt][kt], ai[nt], 0, 0, 0);
#pragma unroll
                for (int nt = 0; nt < 3; ++nt)
                    ai[nt] = __builtin_amdgcn_mfma_f32_16x16x32_bf16(xl, bih[nt][kt], ai[nt], 0, 0, 0);
            }
#pragma unroll
            for (int s = 0; s < 3; ++s)
#pragma unroll
                for (int i = 0; i < 4; ++i)
                    pgi[kw][s][prow + i][lrow] = ai[s][i];
            __syncthreads();
        }
    }

    if (tid < 256)
        out[(size_t)(TT - 1) * 65536u + brow * DD + ce] = ys_prev;
}

extern "C" void kernel_launch(void* const* d_in, const int* in_sizes, int n_in,
                              void* d_out, int out_size, void* d_ws, size_t ws_size,
                              hipStream_t stream) {
    const float* x = (const float*)d_in[0];
    const float* Wi = (const float*)d_in[1];
    const float* bi = (const float*)d_in[2];
    const float* Wh = (const float*)d_in[3];
    const float* bhn = (const float*)d_in[4];
    const unsigned char* resets = (const unsigned char*)d_in[5];
    float* out = (float*)d_out;
    unsigned char* ws = (unsigned char*)d_ws;

    if (ws_size < WS_NEED) return;

    hipLaunchKernelGGL(pack_x_kernel, dim3(16384), dim3(256), 0, stream, x, (unsigned*)out);
    hipLaunchKernelGGL(prep_kernel, dim3(257), dim3(256), 0, stream, resets, ws);

    void* args[] = {(void*)&Wi, (void*)&bi, (void*)&Wh, (void*)&bhn,
                    (void*)&resets, (void*)&out, (void*)&ws};
    hipError_t err = hipLaunchCooperativeKernel((const void*)gru_kernel, dim3(256), dim3(512),
                                                args, 0, stream);
    if (err != hipSuccess) {
        hipLaunchKernelGGL(gru_kernel, dim3(256), dim3(512), 0, stream,
                           Wi, bi, Wh, bhn, resets, out, ws);
    }
}